// Round 3
// baseline (273.445 us; speedup 1.0000x reference)
//
#include <hip/hip_runtime.h>

// EarlyRewardLoss, N=4096, T=365, C=32.
// R7 = R6 resubmitted verbatim (R6 bench was an infra failure: container
// acquisition failed twice; kernel never ran).
// R6 = R5 with the reduce-range bug fixed (R5 wrote 4096 per-row partials
// but reduce_kernel only summed the first 1024 -> absmax 16.2).
//  - 1024 blocks x 256 thr, 4 rows/block, __launch_bounds__(256,4)
//    -> 16 waves/CU: the ENTIRE grid is co-resident (no block-drain tail).
//  - Streaming phase: 12 independent float4/thread per row, branchless
//    sel4, no dynamic register indexing -> no scratch; 4 rows amortize
//    the barriers 4x.
//  - Scan phase: wave w scans row w concurrently. Lane owns t in
//    [6*lane, 6*lane+6): local exclusive prefix products in registers,
//    ONE 6-step shfl_up scan across lanes (dependent-shfl chain ~36 -> ~7).
// Kernel 2: single block reduces all 4096 per-row partials. No atomics.

constexpr int   T_DIM      = 365;
constexpr int   C_DIM      = 32;
constexpr int   N_DIM      = 4096;
constexpr int   RPB        = 4;                 // rows per block
constexpr int   NBLK       = N_DIM / RPB;       // 1024
constexpr float EPS_OVER_T = 10.0f / 365.0f;
constexpr int   F4_PER_ROW = T_DIM * C_DIM / 4; // 2920
constexpr int   ELEMS_YP   = RPB * T_DIM;       // 1460

__device__ __forceinline__ float sel4(float4 v, unsigned d) {
    // branchless: 3 v_cndmask, no memory, no address-of
    float r = (d == 1u) ? v.y : v.x;
    r       = (d == 2u) ? v.z : r;
    r       = (d == 3u) ? v.w : r;
    return r;
}

__global__ __launch_bounds__(256, 4)
void row_kernel(const float* __restrict__ logp,   // [N,T,C]
                const float* __restrict__ ps,     // [N,T]
                const int*   __restrict__ yt,     // [N,T]
                float* __restrict__ partial)      // [N_DIM]
{
    const int tid  = threadIdx.x;
    const int row0 = blockIdx.x * RPB;

    __shared__ int   sy [RPB][T_DIM];
    __shared__ float sps[RPB][T_DIM];
    __shared__ float slp[RPB][T_DIM];

    // ---- coalesced yt/ps staging for all 4 rows (contiguous in memory) ----
    {
        const int*   ytr = yt + (size_t)row0 * T_DIM;
        const float* psr = ps + (size_t)row0 * T_DIM;
        int*   syf  = &sy[0][0];
        float* spsf = &sps[0][0];
        #pragma unroll
        for (int j = 0; j < (ELEMS_YP + 255) / 256; ++j) {
            const int e = tid + j * 256;
            if (e < ELEMS_YP) {
                syf[e]  = ytr[e];
                spsf[e] = psr[e];
            }
        }
    }
    __syncthreads();

    // ---- stream 4 rows of logp; 12 independent float4 loads per batch ----
    #pragma unroll 1
    for (int r = 0; r < RPB; ++r) {
        const float4* lp4 = (const float4*)(logp + (size_t)(row0 + r) * (T_DIM * C_DIM));
        float4 v0, v1, v2, v3, v4, v5, v6, v7, v8, v9, v10, v11;
        const int f0 = tid;
        v0  = lp4[f0          ];
        v1  = lp4[f0 +  1*256 ];
        v2  = lp4[f0 +  2*256 ];
        v3  = lp4[f0 +  3*256 ];
        v4  = lp4[f0 +  4*256 ];
        v5  = lp4[f0 +  5*256 ];
        v6  = lp4[f0 +  6*256 ];
        v7  = lp4[f0 +  7*256 ];
        v8  = lp4[f0 +  8*256 ];
        v9  = lp4[f0 +  9*256 ];
        v10 = lp4[f0 + 10*256 ];
        if (f0 + 11*256 < F4_PER_ROW) v11 = lp4[f0 + 11*256];

        #define SELSTORE(vv, jj)                                         \
        do {                                                             \
            const int f = tid + (jj) * 256;                              \
            if (f < F4_PER_ROW) {                                        \
                const int t  = f >> 3;                                   \
                const int c0 = (f & 7) << 2;                             \
                const unsigned d = (unsigned)(sy[r][t] - c0);            \
                if (d < 4u) slp[r][t] = sel4(vv, d);                     \
            }                                                            \
        } while (0)

        SELSTORE(v0, 0);  SELSTORE(v1, 1);  SELSTORE(v2, 2);
        SELSTORE(v3, 3);  SELSTORE(v4, 4);  SELSTORE(v5, 5);
        SELSTORE(v6, 6);  SELSTORE(v7, 7);  SELSTORE(v8, 8);
        SELSTORE(v9, 9);  SELSTORE(v10,10); SELSTORE(v11,11);
        #undef SELSTORE
    }
    __syncthreads();

    // ---- wave w scans row w; lane owns t in [6*lane, 6*lane+6) ----
    {
        const int w    = tid >> 6;
        const int lane = tid & 63;
        const float* spw = sps[w];
        const float* slw = slp[w];

        // d_t = ps[t+1] for t<T-1, d_{T-1} = 1, pad d = 0 (s=1, inert).
        float dj[6], pj[6];
        float L = 1.0f;
        #pragma unroll
        for (int j = 0; j < 6; ++j) {
            const int t = lane * 6 + j;
            float dv;
            if (t < T_DIM - 1)       dv = spw[t + 1];
            else if (t == T_DIM - 1) dv = 1.0f;
            else                     dv = 0.0f;
            dj[j] = dv;
            pj[j] = L;             // exclusive local prefix of (1-d)
            L *= (1.0f - dv);
        }

        // single inclusive wave scan of per-lane product
        #pragma unroll
        for (int off = 1; off < 64; off <<= 1) {
            const float o = __shfl_up(L, off);
            if (lane >= off) L *= o;
        }
        float E = __shfl_up(L, 1);  // exclusive across lanes
        if (lane == 0) E = 1.0f;

        float cl = 0.0f, er = 0.0f;
        #pragma unroll
        for (int j = 0; j < 6; ++j) {
            const int t = lane * 6 + j;
            if (t < T_DIM) {
                const float lp = slw[t];
                const float pt = dj[j] * E * pj[j] + EPS_OVER_T;
                cl += lp * pt;
                er += pt * __expf(lp) * (1.0f - (float)t * (1.0f / T_DIM));
            }
        }

        #pragma unroll
        for (int off = 32; off > 0; off >>= 1) {
            cl += __shfl_xor(cl, off);
            er += __shfl_xor(er, off);
        }
        if (lane == 0)
            partial[row0 + w] = (-0.5f * (cl + er)) * (1.0f / (float)N_DIM);
    }
}

__global__ __launch_bounds__(256)
void reduce_kernel(const float* __restrict__ partial, float* __restrict__ out)
{
    const int tid = threadIdx.x;
    float s = 0.0f;
    #pragma unroll
    for (int j = 0; j < N_DIM / 256; ++j) s += partial[tid + j * 256];

    #pragma unroll
    for (int off = 32; off > 0; off >>= 1) s += __shfl_xor(s, off);

    __shared__ float w[4];
    if ((tid & 63) == 0) w[tid >> 6] = s;
    __syncthreads();
    if (tid == 0) out[0] = w[0] + w[1] + w[2] + w[3];
}

extern "C" void kernel_launch(void* const* d_in, const int* in_sizes, int n_in,
                              void* d_out, int out_size, void* d_ws, size_t ws_size,
                              hipStream_t stream) {
    const float* logp = (const float*)d_in[0];
    const float* ps   = (const float*)d_in[1];
    const int*   yt   = (const int*)d_in[2];
    float* out     = (float*)d_out;
    float* partial = (float*)d_ws;   // 4096 floats = 16 KB

    row_kernel<<<NBLK, 256, 0, stream>>>(logp, ps, yt, partial);
    reduce_kernel<<<1, 256, 0, stream>>>(partial, out);
}

// Round 4
// 272.702 us; speedup vs baseline: 1.0027x; 1.0027x over previous
//
#include <hip/hip_runtime.h>

// EarlyRewardLoss, N=4096, T=365, C=32.
// R8: single fused kernel.
//  Controllable budget analysis (R7 counters): timed region = 2 harness
//  poison-fills (~224 us) + our kernels (~49 us). Floor for our part is
//  ~32 us (203 MB stream @ 6.3 TB/s). R8 removes the remaining non-stream
//  overhead:
//   - scan HOISTED before the stream: Pt and Pt*(1-t/T) are computed into
//     LDS first, so each streaming hit accumulates into a register
//     directly (acc += lp*sA[t] + expf(lp)*sB[t]). No slp round-trip,
//     no post-stream scan tail.
//   - reduce_kernel eliminated: per-block wave reduce + ONE atomicAdd per
//     block to out (1024 adds, ~2 us, vs ~5 us dependent launch).
//  Streaming structure unchanged from R7 (12 independent float4/thread,
//  branchless sel4, no dynamic register indexing -> no scratch).
//  1024 blocks x 256 thr, 4 rows/block, __launch_bounds__(256,4):
//  entire grid co-resident (16 waves/CU).

constexpr int   T_DIM      = 365;
constexpr int   C_DIM      = 32;
constexpr int   N_DIM      = 4096;
constexpr int   RPB        = 4;                 // rows per block
constexpr int   NBLK       = N_DIM / RPB;       // 1024
constexpr float EPS_OVER_T = 10.0f / 365.0f;
constexpr int   F4_PER_ROW = T_DIM * C_DIM / 4; // 2920
constexpr int   ELEMS_YP   = RPB * T_DIM;       // 1460

__device__ __forceinline__ float sel4(float4 v, unsigned d) {
    // branchless: 3 v_cndmask, no memory, no address-of
    float r = (d == 1u) ? v.y : v.x;
    r       = (d == 2u) ? v.z : r;
    r       = (d == 3u) ? v.w : r;
    return r;
}

__global__ __launch_bounds__(256, 4)
void fused_kernel(const float* __restrict__ logp,   // [N,T,C]
                  const float* __restrict__ ps,     // [N,T]
                  const int*   __restrict__ yt,     // [N,T]
                  float* __restrict__ out)          // [1], zeroed by harness
{
    const int tid  = threadIdx.x;
    const int row0 = blockIdx.x * RPB;

    __shared__ int   sy[RPB][T_DIM];
    __shared__ float sA[RPB][T_DIM];   // Pt
    __shared__ float sB[RPB][T_DIM];   // Pt * (1 - t/T); staged ps lives here first
    __shared__ float wsum[RPB];

    // ---- coalesced yt/ps staging for all 4 rows (contiguous in memory) ----
    {
        const int*   ytr = yt + (size_t)row0 * T_DIM;
        const float* psr = ps + (size_t)row0 * T_DIM;
        int*   syf  = &sy[0][0];
        float* spsf = &sB[0][0];       // ps staged into sB, consumed by scan
        #pragma unroll
        for (int j = 0; j < (ELEMS_YP + 255) / 256; ++j) {
            const int e = tid + j * 256;
            if (e < ELEMS_YP) {
                syf[e]  = ytr[e];
                spsf[e] = psr[e];
            }
        }
    }
    __syncthreads();

    // ---- wave w: scan row w, writing Pt weights into sA/sB ----
    // Lane owns t in [6*lane, 6*lane+6). All LDS reads (ps) complete before
    // any writes (Pt) within the wave: reads in first loop, writes after scan.
    {
        const int w    = tid >> 6;
        const int lane = tid & 63;
        const float* spw = sB[w];

        // d_t = ps[t+1] for t<T-1, d_{T-1} = 1, pad d = 0 (s=1, inert).
        float dj[6], pj[6];
        float L = 1.0f;
        #pragma unroll
        for (int j = 0; j < 6; ++j) {
            const int t = lane * 6 + j;
            float dv;
            if (t < T_DIM - 1)       dv = spw[t + 1];
            else if (t == T_DIM - 1) dv = 1.0f;
            else                     dv = 0.0f;
            dj[j] = dv;
            pj[j] = L;             // exclusive local prefix of (1-d)
            L *= (1.0f - dv);
        }

        // single inclusive wave scan of per-lane product
        #pragma unroll
        for (int off = 1; off < 64; off <<= 1) {
            const float o = __shfl_up(L, off);
            if (lane >= off) L *= o;
        }
        float E = __shfl_up(L, 1);  // exclusive across lanes
        if (lane == 0) E = 1.0f;

        #pragma unroll
        for (int j = 0; j < 6; ++j) {
            const int t = lane * 6 + j;
            if (t < T_DIM) {
                const float pt = dj[j] * E * pj[j] + EPS_OVER_T;
                sA[w][t] = pt;
                sB[w][t] = pt * (1.0f - (float)t * (1.0f / T_DIM));
            }
        }
    }
    __syncthreads();

    // ---- stream 4 rows of logp; accumulate hits directly ----
    float acc = 0.0f;
    #pragma unroll 1
    for (int r = 0; r < RPB; ++r) {
        const float4* lp4 = (const float4*)(logp + (size_t)(row0 + r) * (T_DIM * C_DIM));
        float4 v0, v1, v2, v3, v4, v5, v6, v7, v8, v9, v10, v11;
        const int f0 = tid;
        v0  = lp4[f0          ];
        v1  = lp4[f0 +  1*256 ];
        v2  = lp4[f0 +  2*256 ];
        v3  = lp4[f0 +  3*256 ];
        v4  = lp4[f0 +  4*256 ];
        v5  = lp4[f0 +  5*256 ];
        v6  = lp4[f0 +  6*256 ];
        v7  = lp4[f0 +  7*256 ];
        v8  = lp4[f0 +  8*256 ];
        v9  = lp4[f0 +  9*256 ];
        v10 = lp4[f0 + 10*256 ];
        if (f0 + 11*256 < F4_PER_ROW) v11 = lp4[f0 + 11*256];

        #define SELACC(vv, jj)                                           \
        do {                                                             \
            const int f = tid + (jj) * 256;                              \
            if (f < F4_PER_ROW) {                                        \
                const int t  = f >> 3;                                   \
                const int c0 = (f & 7) << 2;                             \
                const unsigned d = (unsigned)(sy[r][t] - c0);            \
                if (d < 4u) {                                            \
                    const float lp = sel4(vv, d);                        \
                    acc += lp * sA[r][t] + __expf(lp) * sB[r][t];        \
                }                                                        \
            }                                                            \
        } while (0)

        SELACC(v0, 0);  SELACC(v1, 1);  SELACC(v2, 2);
        SELACC(v3, 3);  SELACC(v4, 4);  SELACC(v5, 5);
        SELACC(v6, 6);  SELACC(v7, 7);  SELACC(v8, 8);
        SELACC(v9, 9);  SELACC(v10,10); SELACC(v11,11);
        #undef SELACC
    }

    // ---- block reduce + one atomicAdd per block ----
    #pragma unroll
    for (int off = 32; off > 0; off >>= 1) acc += __shfl_xor(acc, off);

    const int w    = tid >> 6;
    const int lane = tid & 63;
    if (lane == 0) wsum[w] = acc;
    __syncthreads();
    if (tid == 0) {
        const float blocksum = wsum[0] + wsum[1] + wsum[2] + wsum[3];
        atomicAdd(out, blocksum * (-0.5f / (float)N_DIM));
    }
}

extern "C" void kernel_launch(void* const* d_in, const int* in_sizes, int n_in,
                              void* d_out, int out_size, void* d_ws, size_t ws_size,
                              hipStream_t stream) {
    const float* logp = (const float*)d_in[0];
    const float* ps   = (const float*)d_in[1];
    const int*   yt   = (const int*)d_in[2];
    float* out = (float*)d_out;

    fused_kernel<<<NBLK, 256, 0, stream>>>(logp, ps, yt, out);
}

// Round 5
// 270.505 us; speedup vs baseline: 1.0109x; 1.0081x over previous
//
#include <hip/hip_runtime.h>

// EarlyRewardLoss, N=4096, T=365, C=32.
// R9 = revert to the proven-best R4 structure (269.98 us this session,
// 270.4 us previous session). Session findings that justify this:
//  - Timed region = 2x ~112 us harness poison fills (unconditional, seen
//    even when d_ws is unused) + ~5-8 us fixed overhead + our kernels
//    (~37-45 us vs a provable 31 us floor).
//  - Byte floor is fixed: each (n,t) gather line (128 B) IS the 32-class
//    row, so any algorithm fetches the full 191 MB logp tensor.
//  - Structural rewrites (4 rows/block co-residency, re-associated scan,
//    kernel fusion, atomic reduce) all landed within +-1.2% of this
//    version; 4096 blocks x 256 thr block-per-row is the best measured.
// Kernel 1: block-per-row. Stage sy/sps in LDS; stream the row's 2920
// float4 with 12 independent loads/thread; select logp[t][y[t]] -> slp.
// Wave 0 then does the multiplicative prefix scan (Pt) + reductions.
// Kernel 2: single block reduces 4096 partials. No atomics.

constexpr int   T_DIM      = 365;
constexpr int   C_DIM      = 32;
constexpr int   N_DIM      = 4096;
constexpr float EPS_OVER_T = 10.0f / 365.0f;
constexpr int   F4_PER_ROW = T_DIM * C_DIM / 4;        // 2920
constexpr int   ITERS      = (F4_PER_ROW + 255) / 256; // 12

__device__ __forceinline__ float sel4(float4 v, unsigned d) {
    // branchless: 3 v_cndmask, no memory, no address-of
    float r = (d == 1u) ? v.y : v.x;
    r       = (d == 2u) ? v.z : r;
    r       = (d == 3u) ? v.w : r;
    return r;
}

__global__ __launch_bounds__(256)
void row_kernel(const float* __restrict__ logp,   // [N,T,C]
                const float* __restrict__ ps,     // [N,T]
                const int*   __restrict__ yt,     // [N,T]
                float* __restrict__ partial)      // [N]
{
    const int tid = threadIdx.x;
    const int row = blockIdx.x;

    const float4* lp4 = (const float4*)(logp + (size_t)row * (T_DIM * C_DIM));
    const float*  psr = ps + (size_t)row * T_DIM;
    const int*    ytr = yt + (size_t)row * T_DIM;

    __shared__ int   sy [T_DIM];
    __shared__ float sps[T_DIM];
    __shared__ float slp[T_DIM];

    // ---- coalesced yt/ps row loads -> LDS ----
    const int  t1   = tid + 256;
    const bool has0 = (tid < T_DIM);
    const bool has1 = (t1  < T_DIM);
    int   y0 = 0, y1 = 0;
    float p0 = 0.f, p1 = 0.f;
    if (has0) { y0 = ytr[tid]; p0 = psr[tid]; }
    if (has1) { y1 = ytr[t1];  p1 = psr[t1]; }
    if (has0) { sy[tid] = y0; sps[tid] = p0; }
    if (has1) { sy[t1]  = y1; sps[t1]  = p1; }
    __syncthreads();

    // ---- stream the logp row; 12 independent float4 loads per thread ----
    // Each float4 covers (t = f>>3, classes c0..c0+3, c0 = (f&7)*4).
    {
        float4 v0, v1, v2, v3, v4, v5, v6, v7, v8, v9, v10, v11;
        const int f0 = tid;
        v0  = lp4[f0          ];
        v1  = lp4[f0 +  1*256 ];
        v2  = lp4[f0 +  2*256 ];
        v3  = lp4[f0 +  3*256 ];
        v4  = lp4[f0 +  4*256 ];
        v5  = lp4[f0 +  5*256 ];
        v6  = lp4[f0 +  6*256 ];
        v7  = lp4[f0 +  7*256 ];
        v8  = lp4[f0 +  8*256 ];
        v9  = lp4[f0 +  9*256 ];
        v10 = lp4[f0 + 10*256 ];
        if (f0 + 11*256 < F4_PER_ROW) v11 = lp4[f0 + 11*256];

        #define SELSTORE(vv, jj)                                         \
        do {                                                             \
            const int f = tid + (jj) * 256;                              \
            if (f < F4_PER_ROW) {                                        \
                const int t  = f >> 3;                                   \
                const int c0 = (f & 7) << 2;                             \
                const unsigned d = (unsigned)(sy[t] - c0);               \
                if (d < 4u) slp[t] = sel4(vv, d);                        \
            }                                                            \
        } while (0)

        SELSTORE(v0, 0);  SELSTORE(v1, 1);  SELSTORE(v2, 2);
        SELSTORE(v3, 3);  SELSTORE(v4, 4);  SELSTORE(v5, 5);
        SELSTORE(v6, 6);  SELSTORE(v7, 7);  SELSTORE(v8, 8);
        SELSTORE(v9, 9);  SELSTORE(v10,10); SELSTORE(v11,11);
        #undef SELSTORE
    }
    __syncthreads();

    // ---- wave 0: multiplicative prefix scan + reductions ----
    if (tid < 64) {
        const int lane = tid;
        float carry = 1.0f, cl = 0.0f, er = 0.0f;

        #pragma unroll
        for (int k = 0; k < 6; ++k) {
            const int t = k * 64 + lane;
            float d;
            if (t < T_DIM - 1)       d = sps[t + 1];
            else if (t == T_DIM - 1) d = 1.0f;
            else                     d = 0.0f;    // pad: m=1, no scan effect

            float s = 1.0f - d;
            #pragma unroll
            for (int off = 1; off < 64; off <<= 1) {
                const float o = __shfl_up(s, off);
                if (lane >= off) s *= o;
            }
            float e = __shfl_up(s, 1);
            if (lane == 0) e = 1.0f;

            const float pt = d * carry * e + EPS_OVER_T;
            carry *= __shfl(s, 63);

            if (t < T_DIM) {
                const float lp = slp[t];
                cl += lp * pt;
                er += pt * __expf(lp) * (1.0f - (float)t * (1.0f / T_DIM));
            }
        }

        #pragma unroll
        for (int off = 32; off > 0; off >>= 1) {
            cl += __shfl_xor(cl, off);
            er += __shfl_xor(er, off);
        }
        if (lane == 0)
            partial[row] = (-0.5f * (cl + er)) * (1.0f / (float)N_DIM);
    }
}

__global__ __launch_bounds__(256)
void reduce_kernel(const float* __restrict__ partial, float* __restrict__ out)
{
    const int tid = threadIdx.x;
    float s = 0.0f;
    #pragma unroll
    for (int j = 0; j < N_DIM / 256; ++j) s += partial[tid + j * 256];

    #pragma unroll
    for (int off = 32; off > 0; off >>= 1) s += __shfl_xor(s, off);

    __shared__ float w[4];
    if ((tid & 63) == 0) w[tid >> 6] = s;
    __syncthreads();
    if (tid == 0) out[0] = w[0] + w[1] + w[2] + w[3];
}

extern "C" void kernel_launch(void* const* d_in, const int* in_sizes, int n_in,
                              void* d_out, int out_size, void* d_ws, size_t ws_size,
                              hipStream_t stream) {
    const float* logp = (const float*)d_in[0];
    const float* ps   = (const float*)d_in[1];
    const int*   yt   = (const int*)d_in[2];
    float* out     = (float*)d_out;
    float* partial = (float*)d_ws;   // 4096 floats = 16 KB

    row_kernel<<<N_DIM, 256, 0, stream>>>(logp, ps, yt, partial);
    reduce_kernel<<<1, 256, 0, stream>>>(partial, out);
}